// Round 14
// baseline (134.596 us; speedup 1.0000x reference)
//
#include <hip/hip_runtime.h>
#include <hip/hip_bf16.h>

typedef __attribute__((ext_vector_type(8))) _Float16 f16x8;
typedef __attribute__((ext_vector_type(4))) _Float16 f16x4;
typedef __attribute__((ext_vector_type(2))) _Float16 f16x2;
typedef __attribute__((ext_vector_type(4))) float f32x4;
typedef __attribute__((ext_vector_type(16))) float f32x16;
typedef __attribute__((ext_vector_type(2))) __fp16 fp16v2;

__device__ __forceinline__ void gload16(const void* g, void* l) {
  __builtin_amdgcn_global_load_lds((const __attribute__((address_space(1))) void*)g,
                                   (__attribute__((address_space(3))) void*)l, 16, 0, 0);
}
// raw v_exp_f32 (2^x)
__device__ __forceinline__ float fexp2(float x) {
#if __has_builtin(__builtin_amdgcn_exp2f)
  return __builtin_amdgcn_exp2f(x);
#else
  return exp2f(x);
#endif
}
// single-instruction f32x2 -> f16x2 pack (RTZ)
__device__ __forceinline__ unsigned pk2(float a, float b) {
#if __has_builtin(__builtin_amdgcn_cvt_pkrtz)
  fp16v2 r = __builtin_amdgcn_cvt_pkrtz(a, b);
  return __builtin_bit_cast(unsigned, r);
#else
  f16x2 t;
  t[0] = (_Float16)a;
  t[1] = (_Float16)b;
  return __builtin_bit_cast(unsigned, t);
#endif
}

// ---------------------------------------------------------------- fused casts f32 -> f16
__global__ __launch_bounds__(256) void cast_all(const float* __restrict__ x,
                                                const float* __restrict__ wqkv,
                                                const float* __restrict__ wout,
                                                _Float16* __restrict__ xh,
                                                _Float16* __restrict__ wqkvh,
                                                _Float16* __restrict__ wouth) {
  const int i = (blockIdx.x * 256 + threadIdx.x) * 8;
  const float* s;
  _Float16* d;
  int off;
  if (i < 4194304) {
    s = x; d = xh; off = i;
  } else if (i < 7340032) {
    s = wqkv; d = wqkvh; off = i - 4194304;
  } else {
    s = wout; d = wouth; off = i - 7340032;
  }
  const float4 v0 = *reinterpret_cast<const float4*>(s + off);
  const float4 v1 = *reinterpret_cast<const float4*>(s + off + 4);
  f16x8 h;
  h[0] = (_Float16)v0.x; h[1] = (_Float16)v0.y; h[2] = (_Float16)v0.z; h[3] = (_Float16)v0.w;
  h[4] = (_Float16)v1.x; h[5] = (_Float16)v1.y; h[6] = (_Float16)v1.z; h[7] = (_Float16)v1.w;
  *reinterpret_cast<f16x8*>(d + off) = h;
}

// ---------------------------------------------------------------- QKV GEMM (128x128 tile)
// 2-buffer scheme (structure's best for this shape). Epilogue: j-innermost store
// order so 4 adjacent 32B runs per row issue back-to-back (write-combining).
__global__ __launch_bounds__(256) void gemm_qkv(
    const _Float16* __restrict__ A, const _Float16* __restrict__ Bm,
    const float* __restrict__ bias,
    _Float16* __restrict__ Qo, _Float16* __restrict__ Ko, _Float16* __restrict__ Vto,
    int Ndim, int Kdim) {
  __shared__ __align__(16) _Float16 As[2][4096];
  __shared__ __align__(16) _Float16 Bs[2][4096];
  const int tid = threadIdx.x, lane = tid & 63, wave = tid >> 6;
  const int wm = wave >> 1, wn = wave & 1;
  const int nwg = gridDim.x * gridDim.y;
  int bidl = blockIdx.y * gridDim.x + blockIdx.x;
  bidl = (bidl & 7) * (nwg >> 3) + (bidl >> 3);
  const int m0 = (bidl / gridDim.x) * 128, n0 = (bidl % gridDim.x) * 128;
  const int row = lane & 15, kk = (lane >> 4) * 8;

  const int r0 = tid >> 2, c0 = (tid & 3) * 8;
  const int r1 = (256 + tid) >> 2, c1 = ((256 + tid) & 3) * 8;
  const _Float16* a0 = A + (size_t)(m0 + r0) * Kdim + c0;
  const _Float16* a1 = A + (size_t)(m0 + r1) * Kdim + c1;
  const _Float16* b0 = Bm + (size_t)(n0 + r0) * Kdim + c0;
  const _Float16* b1 = Bm + (size_t)(n0 + r1) * Kdim + c1;

  f32x4 acc[4][4];
#pragma unroll
  for (int i = 0; i < 4; ++i)
#pragma unroll
    for (int j = 0; j < 4; ++j)
#pragma unroll
      for (int q = 0; q < 4; ++q) acc[i][j][q] = 0.f;

  auto STAGE = [&](int bufi, int k0) {
    char* dA = (char*)&As[bufi][0] + (wave * 64) * 16;
    char* dB = (char*)&Bs[bufi][0] + (wave * 64) * 16;
    gload16(a0 + k0, dA);
    gload16(a1 + k0, dA + 4096);
    gload16(b0 + k0, dB);
    gload16(b1 + k0, dB + 4096);
  };

  STAGE(0, 0);
  asm volatile("s_waitcnt vmcnt(0)" ::: "memory");
  __syncthreads();

  for (int k0 = 0; k0 < Kdim; k0 += 32) {
    const int cur = (k0 >> 5) & 1;
    if (k0 + 32 < Kdim) STAGE(cur ^ 1, k0 + 32);
    f16x8 af[4], bf[4];
#pragma unroll
    for (int i = 0; i < 4; ++i)
      af[i] = *reinterpret_cast<const f16x8*>(&As[cur][(wm * 64 + i * 16 + row) * 32 + kk]);
#pragma unroll
    for (int j = 0; j < 4; ++j)
      bf[j] = *reinterpret_cast<const f16x8*>(&Bs[cur][(wn * 64 + j * 16 + row) * 32 + kk]);
#pragma unroll
    for (int i = 0; i < 4; ++i)
#pragma unroll
      for (int j = 0; j < 4; ++j)
        acc[i][j] = __builtin_amdgcn_mfma_f32_16x16x32_f16(af[i], bf[j], acc[i][j], 0, 0, 0);
    asm volatile("s_waitcnt vmcnt(0)" ::: "memory");
    __syncthreads();
  }

  const int part = n0 >> 10;  // block-uniform: 0=Q, 1=K, 2=V
  if (part == 2) {
    // V: Vt[bh][dd][l]; thread's q=0..3 are 4 consecutive l at fixed dd -> f16x4 store
#pragma unroll
    for (int i = 0; i < 4; ++i) {
      const int gm = m0 + wm * 64 + i * 16 + (lane >> 4) * 4;
      const int b = gm >> 11, l0 = gm & 2047;
#pragma unroll
      for (int j = 0; j < 4; ++j) {
        const int gn = n0 + wn * 64 + j * 16 + row;
        const int dD = gn & 1023;
        const int h = dD >> 6, dd = dD & 63;
        const float bb = bias[gn];
        f16x4 v;
#pragma unroll
        for (int q = 0; q < 4; ++q) v[q] = (_Float16)(acc[i][j][q] + bb);
        *reinterpret_cast<f16x4*>(&Vto[((size_t)(b * 16 + h) * 64 + dd) * 2048 + l0]) = v;
      }
    }
  } else {
    float bb[4];
#pragma unroll
    for (int j = 0; j < 4; ++j) bb[j] = bias[n0 + wn * 64 + j * 16 + row];
#pragma unroll
    for (int i = 0; i < 4; ++i) {
#pragma unroll
      for (int q = 0; q < 4; ++q) {
        const int gm = m0 + wm * 64 + i * 16 + (lane >> 4) * 4 + q;
        const int b = gm >> 11, l = gm & 2047;
#pragma unroll
        for (int j = 0; j < 4; ++j) {  // j-inner: 4 adjacent 32B runs back-to-back
          const int gn = n0 + wn * 64 + j * 16 + row;
          const float c = acc[i][j][q] + bb[j];
          const int dD = gn & 1023;
          const int h = dD >> 6, dd = dD & 63;
          const int bh = b * 16 + h;
          if (part == 0)
            Qo[((size_t)bh * 2048 + l) * 64 + dd] = (_Float16)(c * 0.1803368801f);  // /sqrt(hd)*log2e
          else
            Ko[((size_t)bh * 2048 + l) * 64 + dd] = (_Float16)c;
        }
      }
    }
  }
}

// ---------------------------------------------------------------- out-proj GEMM (128x64 tile)
__global__ __launch_bounds__(256) void gemm_out64(
    const _Float16* __restrict__ A, const _Float16* __restrict__ Bm,
    const float* __restrict__ bias, float* __restrict__ Cout, int Ndim, int Kdim) {
  __shared__ __align__(16) _Float16 As[2][4096];
  __shared__ __align__(16) _Float16 Bs[2][2048];
  const int tid = threadIdx.x, lane = tid & 63, wave = tid >> 6;
  const int wm = wave >> 1, wn = wave & 1;
  const int nwg = gridDim.x * gridDim.y;
  int bidl = blockIdx.y * gridDim.x + blockIdx.x;
  bidl = (bidl & 7) * (nwg >> 3) + (bidl >> 3);
  const int m0 = (bidl / gridDim.x) * 128, n0 = (bidl % gridDim.x) * 64;
  const int row = lane & 15, kk = (lane >> 4) * 8;

  const int r0 = tid >> 2, c0 = (tid & 3) * 8;
  const int r1 = (256 + tid) >> 2, c1 = ((256 + tid) & 3) * 8;
  const _Float16* a0 = A + (size_t)(m0 + r0) * Kdim + c0;
  const _Float16* a1 = A + (size_t)(m0 + r1) * Kdim + c1;
  const _Float16* b0 = Bm + (size_t)(n0 + r0) * Kdim + c0;  // rows 0..63

  f32x4 acc[4][2];
#pragma unroll
  for (int i = 0; i < 4; ++i)
#pragma unroll
    for (int j = 0; j < 2; ++j)
#pragma unroll
      for (int q = 0; q < 4; ++q) acc[i][j][q] = 0.f;

  auto STAGE = [&](int bufi, int k0) {
    char* dA = (char*)&As[bufi][0] + (wave * 64) * 16;
    char* dB = (char*)&Bs[bufi][0] + wave * 1024;
    gload16(a0 + k0, dA);
    gload16(a1 + k0, dA + 4096);
    gload16(b0 + k0, dB);
  };

  STAGE(0, 0);
  asm volatile("s_waitcnt vmcnt(0)" ::: "memory");
  __syncthreads();

  for (int k0 = 0; k0 < Kdim; k0 += 32) {
    const int cur = (k0 >> 5) & 1;
    if (k0 + 32 < Kdim) STAGE(cur ^ 1, k0 + 32);
    f16x8 af[4], bf[2];
#pragma unroll
    for (int i = 0; i < 4; ++i)
      af[i] = *reinterpret_cast<const f16x8*>(&As[cur][(wm * 64 + i * 16 + row) * 32 + kk]);
#pragma unroll
    for (int j = 0; j < 2; ++j)
      bf[j] = *reinterpret_cast<const f16x8*>(&Bs[cur][(wn * 32 + j * 16 + row) * 32 + kk]);
#pragma unroll
    for (int i = 0; i < 4; ++i)
#pragma unroll
      for (int j = 0; j < 2; ++j)
        acc[i][j] = __builtin_amdgcn_mfma_f32_16x16x32_f16(af[i], bf[j], acc[i][j], 0, 0, 0);
    asm volatile("s_waitcnt vmcnt(0)" ::: "memory");
    __syncthreads();
  }

#pragma unroll
  for (int i = 0; i < 4; ++i) {
#pragma unroll
    for (int j = 0; j < 2; ++j) {
#pragma unroll
      for (int q = 0; q < 4; ++q) {
        const int gm = m0 + wm * 64 + i * 16 + (lane >> 4) * 4 + q;
        const int gn = n0 + wn * 32 + j * 16 + row;
        Cout[(size_t)gm * Ndim + gn] = acc[i][j][q] + bias[gn];
      }
    }
  }
}

// ---------------------------------------------------------------- flash attention v10
// KVBLK=128 (16 staged iters of 2x64-kv sub-chunks): halves barrier/drain/loop
// overhead vs R8's 32 iters. LDS 64KB (2 buf x 32KB), still 2 blocks/CU.
__global__ __launch_bounds__(256, 2) void attn_fwd(const _Float16* __restrict__ Qh,
                                                   const _Float16* __restrict__ Kh,
                                                   const _Float16* __restrict__ Vth,
                                                   _Float16* __restrict__ AOh) {
  // [buf][K granules 0..1023: 128 rows x 8 | V granules 1024..2047: 64 rows x 16]
  __shared__ __align__(16) uint4 KVs[2][2048];
  const int tid = threadIdx.x, lane = tid & 63, wave = tid >> 6;
  const int bid = blockIdx.x;
  const int bh = bid & 31, qb = bid >> 5;  // bid%8 = bh%8 -> 4 bh per XCD
  const int b = bh >> 4, h = bh & 15;
  const int q0 = qb * 128 + wave * 32;
  const _Float16* Qp = Qh + ((size_t)bh * 2048 + q0) * 64;
  const _Float16* Kp = Kh + (size_t)bh * 2048 * 64;
  const _Float16* Vp = Vth + (size_t)bh * 64 * 2048;
  const int r31 = lane & 31, hl = lane >> 5, r7 = lane & 7, r15 = lane & 15;

  // staging sources: K granule gi=(u*256+tid): row=gi>>3, slot=gi&7, src col = slot^(row&7)
  //                  V granule gj=(u*256+tid): row=gj>>4, slot=gi&15, src chunk = slot^(row&15)
  const _Float16* ksrcs[4];
  const _Float16* vsrcs[4];
#pragma unroll
  for (int u = 0; u < 4; ++u) {
    const int gi = u * 256 + tid;
    const int kr = gi >> 3, ksl = gi & 7;
    ksrcs[u] = Kp + (size_t)kr * 64 + (ksl ^ (kr & 7)) * 8;
    const int vr = gi >> 4, vsl = gi & 15;
    vsrcs[u] = Vp + (size_t)vr * 2048 + (vsl ^ (vr & 15)) * 8;
  }

  // Q B-frags: lane holds col q=r31, d = kd*16 + hl*8 + j
  f16x8 qf[4];
#pragma unroll
  for (int kd = 0; kd < 4; ++kd)
    qf[kd] = *reinterpret_cast<const f16x8*>(&Qp[r31 * 64 + kd * 16 + hl * 8]);

  f32x16 o0, o1;  // O^T acc: [hd=(reg&3)+8*(reg>>2)+4*hl+32*hh][q=r31]
#pragma unroll
  for (int i = 0; i < 16; ++i) { o0[i] = 0.f; o1[i] = 0.f; }
  float mrun = 0.f, lsum = 0.f;  // log2-domain; init 0 safe (lsum=0 -> no phantom mass)

  auto STAGE = [&](uint4* base, int t) {
#pragma unroll
    for (int u = 0; u < 4; ++u) {
      gload16(ksrcs[u] + (size_t)t * 8192, base + u * 256 + tid);
      gload16(vsrcs[u] + t * 128, base + 1024 + u * 256 + tid);
    }
  };

  auto PROCESS = [&](const uint4* cur, int tt) {
    const char* KB = (const char*)cur;
    const char* VB = (const char*)(cur + 1024);

    // S^T - mrun = K . Q^T + (-mrun)
    const float negm = -mrun;
    f32x16 st[2];
    __builtin_amdgcn_s_setprio(1);
#pragma unroll
    for (int t32 = 0; t32 < 2; ++t32) {
#pragma unroll
      for (int i = 0; i < 16; ++i) st[t32][i] = negm;
#pragma unroll
      for (int kd = 0; kd < 4; ++kd) {
        const f16x8 kf = *reinterpret_cast<const f16x8*>(
            KB + (((tt * 64 + t32 * 32 + r31) * 8 + ((kd * 2 + hl) ^ r7)) << 4));
        st[t32] = __builtin_amdgcn_mfma_f32_32x32x16_f16(kf, qf[kd], st[t32], 0, 0, 0);
      }
    }
    __builtin_amdgcn_s_setprio(0);

    // V A-frags: row hh*32+r31, 16B chunk (tt*8 + (t32*2+s)*2 + hl) ^ r15
    f16x8 vf[2][2][2];  // [hh][t32][s]
#pragma unroll
    for (int hh = 0; hh < 2; ++hh)
#pragma unroll
      for (int t32 = 0; t32 < 2; ++t32)
#pragma unroll
        for (int s = 0; s < 2; ++s)
          vf[hh][t32][s] = *reinterpret_cast<const f16x8*>(
              VB + (((hh * 32 + r31) * 16 + ((tt * 8 + (t32 * 2 + s) * 2 + hl) ^ r15)) << 4));

    // tree max over the lane's 32 shifted scores
    float m16[16];
#pragma unroll
    for (int i = 0; i < 16; ++i) m16[i] = fmaxf(st[0][i], st[1][i]);
#pragma unroll
    for (int w = 8; w; w >>= 1)
#pragma unroll
      for (int i = 0; i < 8; ++i)
        if (i < w) m16[i] = fmaxf(m16[i], m16[i + w]);
    const float mt = m16[0];
    // defer-max (T13): rescale only when some lane's tile-max exceeds +11
    if (!__all(mt <= 11.f)) {
      const float mts = fmaxf(mt, __shfl_xor(mt, 32));
      const float d = fmaxf(mts, 0.f);
      const float al = fexp2(-d);
      lsum *= al;
#pragma unroll
      for (int i = 0; i < 16; ++i) { o0[i] *= al; o1[i] *= al; }
      mrun += d;
#pragma unroll
      for (int t32 = 0; t32 < 2; ++t32)
#pragma unroll
        for (int i = 0; i < 16; ++i) st[t32][i] -= d;
    }
    float pr[32];
#pragma unroll
    for (int i = 0; i < 16; ++i) pr[i] = fexp2(st[0][i]);
#pragma unroll
    for (int i = 0; i < 16; ++i) pr[16 + i] = fexp2(st[1][i]);
    float s16[16];
#pragma unroll
    for (int i = 0; i < 16; ++i) s16[i] = pr[i] + pr[16 + i];
#pragma unroll
    for (int w = 8; w; w >>= 1)
#pragma unroll
      for (int i = 0; i < 8; ++i)
        if (i < w) s16[i] += s16[i + w];
    lsum += s16[0];

    // P -> f16 B-frag words (cvt_pkrtz); one-shfl-per-pair exchange across lane^32
    __builtin_amdgcn_s_setprio(1);
#pragma unroll
    for (int t32 = 0; t32 < 2; ++t32) {
#pragma unroll
      for (int s = 0; s < 2; ++s) {
        const int bi = t32 * 16 + s * 8;
        const unsigned Aw = pk2(pr[bi + 0], pr[bi + 1]);
        const unsigned A2 = pk2(pr[bi + 2], pr[bi + 3]);
        const unsigned Bw = pk2(pr[bi + 4], pr[bi + 5]);
        const unsigned B2 = pk2(pr[bi + 6], pr[bi + 7]);
        const unsigned r1 = __shfl_xor(hl ? Aw : Bw, 32);
        const unsigned r2 = __shfl_xor(hl ? A2 : B2, 32);
        union { unsigned u[4]; f16x8 v; } pf;
        pf.u[0] = hl ? r1 : Aw;
        pf.u[1] = hl ? r2 : A2;
        pf.u[2] = hl ? Bw : r1;
        pf.u[3] = hl ? B2 : r2;
        o0 = __builtin_amdgcn_mfma_f32_32x32x16_f16(vf[0][t32][s], pf.v, o0, 0, 0, 0);
        o1 = __builtin_amdgcn_mfma_f32_32x32x16_f16(vf[1][t32][s], pf.v, o1, 0, 0, 0);
      }
    }
    __builtin_amdgcn_s_setprio(0);
  };

  STAGE(KVs[0], 0);
  asm volatile("s_waitcnt vmcnt(0)" ::: "memory");
  __syncthreads();

  for (int t = 0; t < 16; ++t) {
    uint4* cur = KVs[t & 1];
    if (t < 15) STAGE(KVs[(t & 1) ^ 1], t + 1);
    PROCESS(cur, 0);
    PROCESS(cur, 1);
    if (t < 15) {
      asm volatile("s_waitcnt vmcnt(0)" ::: "memory");
      __syncthreads();
    }
  }

  const float ltot = lsum + __shfl_xor(lsum, 32);
  const float inv = 1.f / ltot;
  const size_t orow = (size_t)b * 2048 + q0 + r31;
#pragma unroll
  for (int hh = 0; hh < 2; ++hh) {
#pragma unroll
    for (int rr = 0; rr < 4; ++rr) {
      f16x4 c;
#pragma unroll
      for (int j = 0; j < 4; ++j)
        c[j] = (_Float16)((hh ? o1[rr * 4 + j] : o0[rr * 4 + j]) * inv);
      const int hd = 8 * rr + 4 * hl + 32 * hh;
      *reinterpret_cast<f16x4*>(&AOh[orow * 1024 + h * 64 + hd]) = c;
    }
  }
}

// ---------------------------------------------------------------- launcher
extern "C" void kernel_launch(void* const* d_in, const int* in_sizes, int n_in, void* d_out,
                              int out_size, void* d_ws, size_t ws_size, hipStream_t stream) {
  const float* x = (const float*)d_in[0];
  const float* Wqkv = (const float*)d_in[1];
  const float* bqkv = (const float*)d_in[2];
  const float* Wout = (const float*)d_in[3];
  const float* bout = (const float*)d_in[4];
  float* out = (float*)d_out;

  char* ws = (char*)d_ws;
  _Float16* xh = (_Float16*)(ws);                  // 4096*1024 (8 MB)
  _Float16* wqkvh = (_Float16*)(ws + 8388608);     // 3072*1024 (6 MB)
  _Float16* wouth = (_Float16*)(ws + 14680064);    // 1024*1024 (2 MB)
  _Float16* Qh = (_Float16*)(ws + 16777216);       // [32][2048][64] (8 MB)
  _Float16* Kh = (_Float16*)(ws + 25165824);       // [32][2048][64] (8 MB)
  _Float16* Vth = (_Float16*)(ws + 33554432);      // [32][64][2048] (8 MB)
  _Float16* AOh = (_Float16*)(ws + 41943040);      // 4096*1024 (8 MB)

  cast_all<<<4096, 256, 0, stream>>>(x, Wqkv, Wout, xh, wqkvh, wouth);
  gemm_qkv<<<dim3(24, 32), 256, 0, stream>>>(xh, wqkvh, bqkv, Qh, Kh, Vth, 3072, 1024);
  attn_fwd<<<512, 256, 0, stream>>>(Qh, Kh, Vth, AOh);
  gemm_out64<<<dim3(16, 32), 256, 0, stream>>>(AOh, wouth, bout, out, 1024, 1024);
}

// Round 15
// 128.322 us; speedup vs baseline: 1.0489x; 1.0489x over previous
//
#include <hip/hip_runtime.h>
#include <hip/hip_bf16.h>

typedef __attribute__((ext_vector_type(8))) _Float16 f16x8;
typedef __attribute__((ext_vector_type(4))) _Float16 f16x4;
typedef __attribute__((ext_vector_type(2))) _Float16 f16x2;
typedef __attribute__((ext_vector_type(4))) float f32x4;
typedef __attribute__((ext_vector_type(16))) float f32x16;
typedef __attribute__((ext_vector_type(2))) __fp16 fp16v2;

__device__ __forceinline__ void gload16(const void* g, void* l) {
  __builtin_amdgcn_global_load_lds((const __attribute__((address_space(1))) void*)g,
                                   (__attribute__((address_space(3))) void*)l, 16, 0, 0);
}
// raw v_exp_f32 (2^x)
__device__ __forceinline__ float fexp2(float x) {
#if __has_builtin(__builtin_amdgcn_exp2f)
  return __builtin_amdgcn_exp2f(x);
#else
  return exp2f(x);
#endif
}
// single-instruction f32x2 -> f16x2 pack (RTZ)
__device__ __forceinline__ unsigned pk2(float a, float b) {
#if __has_builtin(__builtin_amdgcn_cvt_pkrtz)
  fp16v2 r = __builtin_amdgcn_cvt_pkrtz(a, b);
  return __builtin_bit_cast(unsigned, r);
#else
  f16x2 t;
  t[0] = (_Float16)a;
  t[1] = (_Float16)b;
  return __builtin_bit_cast(unsigned, t);
#endif
}

// ---------------------------------------------------------------- fused casts f32 -> f16
__global__ __launch_bounds__(256) void cast_all(const float* __restrict__ x,
                                                const float* __restrict__ wqkv,
                                                const float* __restrict__ wout,
                                                _Float16* __restrict__ xh,
                                                _Float16* __restrict__ wqkvh,
                                                _Float16* __restrict__ wouth) {
  const int i = (blockIdx.x * 256 + threadIdx.x) * 8;
  const float* s;
  _Float16* d;
  int off;
  if (i < 4194304) {
    s = x; d = xh; off = i;
  } else if (i < 7340032) {
    s = wqkv; d = wqkvh; off = i - 4194304;
  } else {
    s = wout; d = wouth; off = i - 7340032;
  }
  const float4 v0 = *reinterpret_cast<const float4*>(s + off);
  const float4 v1 = *reinterpret_cast<const float4*>(s + off + 4);
  f16x8 h;
  h[0] = (_Float16)v0.x; h[1] = (_Float16)v0.y; h[2] = (_Float16)v0.z; h[3] = (_Float16)v0.w;
  h[4] = (_Float16)v1.x; h[5] = (_Float16)v1.y; h[6] = (_Float16)v1.z; h[7] = (_Float16)v1.w;
  *reinterpret_cast<f16x8*>(d + off) = h;
}

// ---------------------------------------------------------------- QKV GEMM (128x128 tile)
// 2-buffer scheme + 2D XCD-local mapping: region = bid&7 covers 12n x 8m blocks
// (A 3MB + B-region 3MB fits the 4MB per-XCD L2; old mapping thrashed 6MB B ->
// FETCH 54MB vs 14MB inputs). Within region n-fastest for B reuse.
__global__ __launch_bounds__(256) void gemm_qkv(
    const _Float16* __restrict__ A, const _Float16* __restrict__ Bm,
    const float* __restrict__ bias,
    _Float16* __restrict__ Qo, _Float16* __restrict__ Ko, _Float16* __restrict__ Vto,
    int Ndim, int Kdim) {
  __shared__ __align__(16) _Float16 As[2][4096];
  __shared__ __align__(16) _Float16 Bs[2][4096];
  const int tid = threadIdx.x, lane = tid & 63, wave = tid >> 6;
  const int wm = wave >> 1, wn = wave & 1;
  const int bid = blockIdx.y * gridDim.x + blockIdx.x;  // 0..767
  const int region = bid & 7, idx = bid >> 3;           // 8 regions x 96 blocks
  const int n0 = ((region & 1) * 12 + idx % 12) * 128;  // region: 12n x 8m
  const int m0 = ((region >> 1) * 8 + idx / 12) * 128;
  const int row = lane & 15, kk = (lane >> 4) * 8;

  const int r0 = tid >> 2, c0 = (tid & 3) * 8;
  const int r1 = (256 + tid) >> 2, c1 = ((256 + tid) & 3) * 8;
  const _Float16* a0 = A + (size_t)(m0 + r0) * Kdim + c0;
  const _Float16* a1 = A + (size_t)(m0 + r1) * Kdim + c1;
  const _Float16* b0 = Bm + (size_t)(n0 + r0) * Kdim + c0;
  const _Float16* b1 = Bm + (size_t)(n0 + r1) * Kdim + c1;

  f32x4 acc[4][4];
#pragma unroll
  for (int i = 0; i < 4; ++i)
#pragma unroll
    for (int j = 0; j < 4; ++j)
#pragma unroll
      for (int q = 0; q < 4; ++q) acc[i][j][q] = 0.f;

  auto STAGE = [&](int bufi, int k0) {
    char* dA = (char*)&As[bufi][0] + (wave * 64) * 16;
    char* dB = (char*)&Bs[bufi][0] + (wave * 64) * 16;
    gload16(a0 + k0, dA);
    gload16(a1 + k0, dA + 4096);
    gload16(b0 + k0, dB);
    gload16(b1 + k0, dB + 4096);
  };

  STAGE(0, 0);
  asm volatile("s_waitcnt vmcnt(0)" ::: "memory");
  __syncthreads();

  for (int k0 = 0; k0 < Kdim; k0 += 32) {
    const int cur = (k0 >> 5) & 1;
    if (k0 + 32 < Kdim) STAGE(cur ^ 1, k0 + 32);
    f16x8 af[4], bf[4];
#pragma unroll
    for (int i = 0; i < 4; ++i)
      af[i] = *reinterpret_cast<const f16x8*>(&As[cur][(wm * 64 + i * 16 + row) * 32 + kk]);
#pragma unroll
    for (int j = 0; j < 4; ++j)
      bf[j] = *reinterpret_cast<const f16x8*>(&Bs[cur][(wn * 64 + j * 16 + row) * 32 + kk]);
#pragma unroll
    for (int i = 0; i < 4; ++i)
#pragma unroll
      for (int j = 0; j < 4; ++j)
        acc[i][j] = __builtin_amdgcn_mfma_f32_16x16x32_f16(af[i], bf[j], acc[i][j], 0, 0, 0);
    asm volatile("s_waitcnt vmcnt(0)" ::: "memory");
    __syncthreads();
  }

  const int part = n0 >> 10;  // block-uniform: 0=Q, 1=K, 2=V
  if (part == 2) {
    // V: Vt[bh][dd][l]; thread's q=0..3 are 4 consecutive l at fixed dd -> f16x4 store
#pragma unroll
    for (int i = 0; i < 4; ++i) {
      const int gm = m0 + wm * 64 + i * 16 + (lane >> 4) * 4;
      const int b = gm >> 11, l0 = gm & 2047;
#pragma unroll
      for (int j = 0; j < 4; ++j) {
        const int gn = n0 + wn * 64 + j * 16 + row;
        const int dD = gn & 1023;
        const int h = dD >> 6, dd = dD & 63;
        const float bb = bias[gn];
        f16x4 v;
#pragma unroll
        for (int q = 0; q < 4; ++q) v[q] = (_Float16)(acc[i][j][q] + bb);
        *reinterpret_cast<f16x4*>(&Vto[((size_t)(b * 16 + h) * 64 + dd) * 2048 + l0]) = v;
      }
    }
  } else {
    float bb[4];
#pragma unroll
    for (int j = 0; j < 4; ++j) bb[j] = bias[n0 + wn * 64 + j * 16 + row];
#pragma unroll
    for (int i = 0; i < 4; ++i) {
#pragma unroll
      for (int q = 0; q < 4; ++q) {
        const int gm = m0 + wm * 64 + i * 16 + (lane >> 4) * 4 + q;
        const int b = gm >> 11, l = gm & 2047;
#pragma unroll
        for (int j = 0; j < 4; ++j) {  // j-inner: 4 adjacent 32B runs back-to-back
          const int gn = n0 + wn * 64 + j * 16 + row;
          const float c = acc[i][j][q] + bb[j];
          const int dD = gn & 1023;
          const int h = dD >> 6, dd = dD & 63;
          const int bh = b * 16 + h;
          if (part == 0)
            Qo[((size_t)bh * 2048 + l) * 64 + dd] = (_Float16)(c * 0.1803368801f);  // /sqrt(hd)*log2e
          else
            Ko[((size_t)bh * 2048 + l) * 64 + dd] = (_Float16)c;
        }
      }
    }
  }
}

// ---------------------------------------------------------------- out-proj GEMM (128x64 tile)
__global__ __launch_bounds__(256) void gemm_out64(
    const _Float16* __restrict__ A, const _Float16* __restrict__ Bm,
    const float* __restrict__ bias, float* __restrict__ Cout, int Ndim, int Kdim) {
  __shared__ __align__(16) _Float16 As[2][4096];
  __shared__ __align__(16) _Float16 Bs[2][2048];
  const int tid = threadIdx.x, lane = tid & 63, wave = tid >> 6;
  const int wm = wave >> 1, wn = wave & 1;
  const int nwg = gridDim.x * gridDim.y;
  int bidl = blockIdx.y * gridDim.x + blockIdx.x;
  bidl = (bidl & 7) * (nwg >> 3) + (bidl >> 3);
  const int m0 = (bidl / gridDim.x) * 128, n0 = (bidl % gridDim.x) * 64;
  const int row = lane & 15, kk = (lane >> 4) * 8;

  const int r0 = tid >> 2, c0 = (tid & 3) * 8;
  const int r1 = (256 + tid) >> 2, c1 = ((256 + tid) & 3) * 8;
  const _Float16* a0 = A + (size_t)(m0 + r0) * Kdim + c0;
  const _Float16* a1 = A + (size_t)(m0 + r1) * Kdim + c1;
  const _Float16* b0 = Bm + (size_t)(n0 + r0) * Kdim + c0;  // rows 0..63

  f32x4 acc[4][2];
#pragma unroll
  for (int i = 0; i < 4; ++i)
#pragma unroll
    for (int j = 0; j < 2; ++j)
#pragma unroll
      for (int q = 0; q < 4; ++q) acc[i][j][q] = 0.f;

  auto STAGE = [&](int bufi, int k0) {
    char* dA = (char*)&As[bufi][0] + (wave * 64) * 16;
    char* dB = (char*)&Bs[bufi][0] + wave * 1024;
    gload16(a0 + k0, dA);
    gload16(a1 + k0, dA + 4096);
    gload16(b0 + k0, dB);
  };

  STAGE(0, 0);
  asm volatile("s_waitcnt vmcnt(0)" ::: "memory");
  __syncthreads();

  for (int k0 = 0; k0 < Kdim; k0 += 32) {
    const int cur = (k0 >> 5) & 1;
    if (k0 + 32 < Kdim) STAGE(cur ^ 1, k0 + 32);
    f16x8 af[4], bf[2];
#pragma unroll
    for (int i = 0; i < 4; ++i)
      af[i] = *reinterpret_cast<const f16x8*>(&As[cur][(wm * 64 + i * 16 + row) * 32 + kk]);
#pragma unroll
    for (int j = 0; j < 2; ++j)
      bf[j] = *reinterpret_cast<const f16x8*>(&Bs[cur][(wn * 32 + j * 16 + row) * 32 + kk]);
#pragma unroll
    for (int i = 0; i < 4; ++i)
#pragma unroll
      for (int j = 0; j < 2; ++j)
        acc[i][j] = __builtin_amdgcn_mfma_f32_16x16x32_f16(af[i], bf[j], acc[i][j], 0, 0, 0);
    asm volatile("s_waitcnt vmcnt(0)" ::: "memory");
    __syncthreads();
  }

#pragma unroll
  for (int i = 0; i < 4; ++i) {
#pragma unroll
    for (int j = 0; j < 2; ++j) {
#pragma unroll
      for (int q = 0; q < 4; ++q) {
        const int gm = m0 + wm * 64 + i * 16 + (lane >> 4) * 4 + q;
        const int gn = n0 + wn * 32 + j * 16 + row;
        Cout[(size_t)gm * Ndim + gn] = acc[i][j][q] + bias[gn];
      }
    }
  }
}

// ---------------------------------------------------------------- flash attention (R8/R13 config)
// Single-pass 2048 kv, KVBLK=64 (32 iters), 32x32x16 MFMA, 4 waves x 32 q-rows.
// R14's KVBLK=128 regressed (59.2 vs 55.5); this is the best-measured config.
__global__ __launch_bounds__(256, 2) void attn_fwd(const _Float16* __restrict__ Qh,
                                                   const _Float16* __restrict__ Kh,
                                                   const _Float16* __restrict__ Vth,
                                                   _Float16* __restrict__ AOh) {
  __shared__ __align__(16) uint4 KVs[2][1024];  // [buf][K granules 0..511 | V 512..1023]
  const int tid = threadIdx.x, lane = tid & 63, wave = tid >> 6;
  const int bid = blockIdx.x;
  const int bh = bid & 31, qb = bid >> 5;  // bid%8 = bh%8 -> 4 bh per XCD
  const int b = bh >> 4, h = bh & 15;
  const int q0 = qb * 128 + wave * 32;
  const _Float16* Qp = Qh + ((size_t)bh * 2048 + q0) * 64;
  const _Float16* Kp = Kh + (size_t)bh * 2048 * 64;
  const _Float16* Vp = Vth + (size_t)bh * 64 * 2048;
  const int r31 = lane & 31, hl = lane >> 5, r7 = lane & 7;

  const int kr0 = tid >> 3, ks0 = (tid & 7) ^ (kr0 & 7);
  const int kr1 = (256 + tid) >> 3, ks1 = ((256 + tid) & 7) ^ (kr1 & 7);
  const _Float16* ksrc0 = Kp + (size_t)kr0 * 64 + ks0 * 8;
  const _Float16* ksrc1 = Kp + (size_t)kr1 * 64 + ks1 * 8;
  const _Float16* vsrc0 = Vp + (size_t)kr0 * 2048 + ks0 * 8;
  const _Float16* vsrc1 = Vp + (size_t)kr1 * 2048 + ks1 * 8;

  // Q B-frags: lane holds col q=r31, d = kd*16 + hl*8 + j
  f16x8 qf[4];
#pragma unroll
  for (int kd = 0; kd < 4; ++kd)
    qf[kd] = *reinterpret_cast<const f16x8*>(&Qp[r31 * 64 + kd * 16 + hl * 8]);

  f32x16 o0, o1;  // O^T acc: [hd=(reg&3)+8*(reg>>2)+4*hl+32*hh][q=r31]
#pragma unroll
  for (int i = 0; i < 16; ++i) { o0[i] = 0.f; o1[i] = 0.f; }
  float mrun = 0.f, lsum = 0.f;  // log2-domain; init 0 safe (lsum=0 -> no phantom mass)

  auto STAGE = [&](uint4* base, int t) {
    gload16(ksrc0 + (size_t)t * 4096, base + wave * 64);
    gload16(ksrc1 + (size_t)t * 4096, base + 256 + wave * 64);
    gload16(vsrc0 + t * 64, base + 512 + wave * 64);
    gload16(vsrc1 + t * 64, base + 768 + wave * 64);
  };

  auto ITER = [&](int t, uint4* cur, uint4* nxt) {
    if (t < 31) STAGE(nxt, t + 1);
    const char* KB = (const char*)cur;
    const char* VB = (const char*)(cur + 512);

    // S^T - mrun = K . Q^T + (-mrun): softmax shift folded into C-init
    const float negm = -mrun;
    f32x16 st[2];
    __builtin_amdgcn_s_setprio(1);
#pragma unroll
    for (int t32 = 0; t32 < 2; ++t32) {
#pragma unroll
      for (int i = 0; i < 16; ++i) st[t32][i] = negm;
#pragma unroll
      for (int kd = 0; kd < 4; ++kd) {
        const f16x8 kf = *reinterpret_cast<const f16x8*>(
            KB + (((t32 * 32 + r31) * 8 + ((kd * 2 + hl) ^ r7)) << 4));
        st[t32] = __builtin_amdgcn_mfma_f32_32x32x16_f16(kf, qf[kd], st[t32], 0, 0, 0);
      }
    }
    __builtin_amdgcn_s_setprio(0);

    // V A-frags
    f16x8 vf[2][2][2];  // [hh][t32][s]
#pragma unroll
    for (int hh = 0; hh < 2; ++hh)
#pragma unroll
      for (int t32 = 0; t32 < 2; ++t32)
#pragma unroll
        for (int s = 0; s < 2; ++s)
          vf[hh][t32][s] = *reinterpret_cast<const f16x8*>(
              VB + (((hh * 32 + r31) * 8 + (((t32 * 2 + s) * 2 + hl) ^ r7)) << 4));

    // tree max over the lane's 32 shifted scores
    float m16[16];
#pragma unroll
    for (int i = 0; i < 16; ++i) m16[i] = fmaxf(st[0][i], st[1][i]);
#pragma unroll
    for (int w = 8; w; w >>= 1)
#pragma unroll
      for (int i = 0; i < 8; ++i)
        if (i < w) m16[i] = fmaxf(m16[i], m16[i + w]);
    const float mt = m16[0];
    // defer-max (T13): rescale only when some lane's tile-max exceeds +11
    if (!__all(mt <= 11.f)) {
      const float mts = fmaxf(mt, __shfl_xor(mt, 32));
      const float d = fmaxf(mts, 0.f);
      const float al = fexp2(-d);
      lsum *= al;
#pragma unroll
      for (int i = 0; i < 16; ++i) { o0[i] *= al; o1[i] *= al; }
      mrun += d;
#pragma unroll
      for (int t32 = 0; t32 < 2; ++t32)
#pragma unroll
        for (int i = 0; i < 16; ++i) st[t32][i] -= d;
    }
    float pr[32];
#pragma unroll
    for (int i = 0; i < 16; ++i) pr[i] = fexp2(st[0][i]);
#pragma unroll
    for (int i = 0; i < 16; ++i) pr[16 + i] = fexp2(st[1][i]);
    float s16[16];
#pragma unroll
    for (int i = 0; i < 16; ++i) s16[i] = pr[i] + pr[16 + i];
#pragma unroll
    for (int w = 8; w; w >>= 1)
#pragma unroll
      for (int i = 0; i < 8; ++i)
        if (i < w) s16[i] += s16[i + w];
    lsum += s16[0];

    // P -> f16 B-frag words (cvt_pkrtz); one-shfl-per-pair exchange across lane^32
    __builtin_amdgcn_s_setprio(1);
#pragma unroll
    for (int t32 = 0; t32 < 2; ++t32) {
#pragma unroll
      for (int s = 0; s < 2; ++s) {
        const int bi = t32 * 16 + s * 8;
        const unsigned Aw = pk2(pr[bi + 0], pr[bi + 1]);
        const unsigned A2 = pk2(pr[bi + 2], pr[bi + 3]);
        const unsigned Bw = pk2(pr[bi + 4], pr[bi + 5]);
        const unsigned B2 = pk2(pr[bi + 6], pr[bi + 7]);
        const unsigned r1 = __shfl_xor(hl ? Aw : Bw, 32);
        const unsigned r2 = __shfl_xor(hl ? A2 : B2, 32);
        union { unsigned u[4]; f16x8 v; } pf;
        pf.u[0] = hl ? r1 : Aw;
        pf.u[1] = hl ? r2 : A2;
        pf.u[2] = hl ? Bw : r1;
        pf.u[3] = hl ? B2 : r2;
        o0 = __builtin_amdgcn_mfma_f32_32x32x16_f16(vf[0][t32][s], pf.v, o0, 0, 0, 0);
        o1 = __builtin_amdgcn_mfma_f32_32x32x16_f16(vf[1][t32][s], pf.v, o1, 0, 0, 0);
      }
    }
    __builtin_amdgcn_s_setprio(0);

    if (t < 31) {
      asm volatile("s_waitcnt vmcnt(0)" ::: "memory");
      __syncthreads();
    }
  };

  STAGE(KVs[0], 0);
  asm volatile("s_waitcnt vmcnt(0)" ::: "memory");
  __syncthreads();

  for (int tt = 0; tt < 16; ++tt) {
    ITER(2 * tt, KVs[0], KVs[1]);
    ITER(2 * tt + 1, KVs[1], KVs[0]);
  }

  const float ltot = lsum + __shfl_xor(lsum, 32);
  const float inv = 1.f / ltot;
  const size_t orow = (size_t)b * 2048 + q0 + r31;
#pragma unroll
  for (int hh = 0; hh < 2; ++hh) {
#pragma unroll
    for (int rr = 0; rr < 4; ++rr) {
      f16x4 c;
#pragma unroll
      for (int j = 0; j < 4; ++j)
        c[j] = (_Float16)((hh ? o1[rr * 4 + j] : o0[rr * 4 + j]) * inv);
      const int hd = 8 * rr + 4 * hl + 32 * hh;
      *reinterpret_cast<f16x4*>(&AOh[orow * 1024 + h * 64 + hd]) = c;
    }
  }
}

// ---------------------------------------------------------------- launcher
extern "C" void kernel_launch(void* const* d_in, const int* in_sizes, int n_in, void* d_out,
                              int out_size, void* d_ws, size_t ws_size, hipStream_t stream) {
  const float* x = (const float*)d_in[0];
  const float* Wqkv = (const float*)d_in[1];
  const float* bqkv = (const float*)d_in[2];
  const float* Wout = (const float*)d_in[3];
  const float* bout = (const float*)d_in[4];
  float* out = (float*)d_out;

  char* ws = (char*)d_ws;
  _Float16* xh = (_Float16*)(ws);                  // 4096*1024 (8 MB)
  _Float16* wqkvh = (_Float16*)(ws + 8388608);     // 3072*1024 (6 MB)
  _Float16* wouth = (_Float16*)(ws + 14680064);    // 1024*1024 (2 MB)
  _Float16* Qh = (_Float16*)(ws + 16777216);       // [32][2048][64] (8 MB)
  _Float16* Kh = (_Float16*)(ws + 25165824);       // [32][2048][64] (8 MB)
  _Float16* Vth = (_Float16*)(ws + 33554432);      // [32][64][2048] (8 MB)
  _Float16* AOh = (_Float16*)(ws + 41943040);      // 4096*1024 (8 MB)

  cast_all<<<4096, 256, 0, stream>>>(x, Wqkv, Wout, xh, wqkvh, wouth);
  gemm_qkv<<<dim3(24, 32), 256, 0, stream>>>(xh, wqkvh, bqkv, Qh, Kh, Vth, 3072, 1024);
  attn_fwd<<<512, 256, 0, stream>>>(Qh, Kh, Vth, AOh);
  gemm_out64<<<dim3(16, 32), 256, 0, stream>>>(AOh, wouth, bout, out, 1024, 1024);
}